// Round 9
// baseline (404.470 us; speedup 1.0000x reference)
//
#include <hip/hip_runtime.h>
#include <hip/hip_bf16.h>
#include <cmath>

#define NN 20000   // nodes
#define NE 60000   // edges
#define NS 3000    // subgraphs
#define NG 128     // graphs
#define HIDN 128   // hidden dim of edge-attr MLP
#define SCB 79     // scan blocks = ceil(NN/256)

typedef float f32x16 __attribute__((ext_vector_type(16)));
typedef __bf16 bf16x8 __attribute__((ext_vector_type(8)));

__device__ __forceinline__ float eluf(float v) { return v > 0.f ? v : expm1f(v); }

// async global->LDS, 16B per lane; lds ptr must be wave-uniform (HW writes base + lane*16)
__device__ __forceinline__ void gload_lds16(const void* g, void* l) {
    __builtin_amdgcn_global_load_lds(
        (const __attribute__((address_space(1))) unsigned int*)g,
        (__attribute__((address_space(3))) unsigned int*)l, 16, 0, 0);
}

// counted vmcnt waits (literal immediates required in asm)
template <int N> struct VmWait;
template <> struct VmWait<0>  { static __device__ __forceinline__ void run() { asm volatile("s_waitcnt vmcnt(0)"  ::: "memory"); } };
template <> struct VmWait<12> { static __device__ __forceinline__ void run() { asm volatile("s_waitcnt vmcnt(12)" ::: "memory"); } };
template <> struct VmWait<16> { static __device__ __forceinline__ void run() { asm volatile("s_waitcnt vmcnt(16)" ::: "memory"); } };
template <> struct VmWait<40> { static __device__ __forceinline__ void run() { asm volatile("s_waitcnt vmcnt(40)" ::: "memory"); } };

// ================= one-time edge sort by dst (counting sort) =================
__global__ void k_hist(const int* __restrict__ dst, int* __restrict__ deg) {
    int e = blockIdx.x * 256 + threadIdx.x;
    if (e < NE) atomicAdd(&deg[dst[e]], 1);
}

// per-block sums of deg
__global__ void k_scan1(const int* __restrict__ deg, int* __restrict__ bsum) {
    __shared__ int s[256];
    const int t = threadIdx.x;
    int i = blockIdx.x * 256 + t;
    s[t] = (i < NN) ? deg[i] : 0;
    __syncthreads();
#pragma unroll
    for (int off = 128; off > 0; off >>= 1) {
        if (t < off) s[t] += s[t + off];
        __syncthreads();
    }
    if (t == 0) bsum[blockIdx.x] = s[0];
}

// exclusive scan of SCB block sums (1 block, 128 threads)
__global__ void k_scan2(const int* __restrict__ bsum, int* __restrict__ boff) {
    __shared__ int s[SCB];
    const int t = threadIdx.x;
    if (t < SCB) s[t] = bsum[t];
    __syncthreads();
    if (t == 0) {
        int acc = 0;
        for (int i = 0; i < SCB; ++i) { int v = s[i]; s[i] = acc; acc += v; }
    }
    __syncthreads();
    if (t < SCB) boff[t] = s[t];
}

// block-local inclusive scan + block offset -> rowptr
__global__ void k_scan3(const int* __restrict__ deg, const int* __restrict__ boff,
                        int* __restrict__ rowptr) {
    __shared__ int s[256];
    const int t = threadIdx.x;
    int i = blockIdx.x * 256 + t;
    int v = (i < NN) ? deg[i] : 0;
    s[t] = v;
    __syncthreads();
#pragma unroll
    for (int off = 1; off < 256; off <<= 1) {
        int a = (t >= off) ? s[t - off] : 0;
        __syncthreads();
        s[t] += a;
        __syncthreads();
    }
    if (i < NN) rowptr[i + 1] = boff[blockIdx.x] + s[t];
    if (i == 0) rowptr[0] = 0;
}

__global__ void k_scatter(const int* __restrict__ src, const int* __restrict__ dst,
                          const int* __restrict__ rowptr, int* __restrict__ tmp,
                          int* __restrict__ eord, int* __restrict__ srcS) {
    int e = blockIdx.x * 256 + threadIdx.x;
    if (e >= NE) return;
    int d = dst[e];
    int pos = rowptr[d] + atomicAdd(&tmp[d], 1);
    eord[pos] = e;
    srcS[pos] = src[e];
}

// ---------------- hT[j][es] = relu(ea[eord[es]] @ w1 + b1)  (128 x E, bf16, TRANSPOSED) ----------------
__global__ void k_hT(const int* __restrict__ eord, const float* __restrict__ ea,
                     const float* __restrict__ w1, const float* __restrict__ b1,
                     __bf16* __restrict__ hT) {
    int idx = blockIdx.x * 256 + threadIdx.x;
    if (idx >= NE * HIDN) return;
    int j = idx / NE, es = idx % NE;   // j-major: coalesced hT writes
    int e = eord[es];
    float s = b1[j];
#pragma unroll
    for (int d = 0; d < 5; ++d) s = fmaf(ea[e * 5 + d], w1[d * HIDN + j], s);
    hT[idx] = (__bf16)fmaxf(s, 0.f);
}

// ---------------- w2t[o][kg] = bf16( kg<128*MI ? w2[kg*MO+o] : b2[(kg-128MI)*MO+o] ) ----------------
template <int MI, int MO>
__global__ void k_w2t(const float* __restrict__ w2, const float* __restrict__ b2,
                      __bf16* __restrict__ w2t) {
    constexpr int KP = 129 * MI;
    constexpr int KF = 128 * MI;
    int idx = blockIdx.x * 256 + threadIdx.x;
    if (idx >= MO * KP) return;
    int o = idx / KP, kg = idx % KP;
    float v = (kg < KF) ? w2[(size_t)kg * MO + o] : b2[(kg - KF) * MO + o];
    w2t[idx] = (__bf16)v;
}

// ---------------- MFMA edge kernel: counted-vmcnt pipeline, in-block K-split ----------------
// msg[j,o] = sum_kg G[j,kg]*w2t[o][kg],  G[j, k*MI+i] = hfac(j,k)*xi[srcS[j],i]
// Block = 4 waves: wave (mg,kh) = 64 edges x full MO x k-half [kh*64, kh*64+64).
// Double-buffered B chunks via global_load_lds; raw barriers with COUNTED vmcnt so
// next-chunk staging loads + h prefetch stay in flight across barriers.
template <int MI, int MO, int XS>
__global__ __launch_bounds__(256, 2) void k_edge4(
    const float* __restrict__ xi, const __bf16* __restrict__ hT,
    const __bf16* __restrict__ w2t, const int* __restrict__ srcS,
    float* __restrict__ msg) {
    constexpr int PH  = MI / 16;        // K-steps per k value
    constexpr int KP  = 129 * MI;       // w2t row length
    constexpr int NT  = MO / 32;        // N tiles
    constexpr int CH  = 16 / (PH * NT); // k values per chunk (ITEMS = 16)
    constexpr int NCH = 64 / CH;        // chunks per k-half
    constexpr int VMK = 8 + 2 * CH;     // counted wait: this iter's 8 stage + 2*CH h loads
    static_assert(CH * PH * NT == 16, "ITEMS must be 16");

    __shared__ __align__(16) __bf16 sb[2][2][16 * 512];   // [kh][dbuf][16KB]

    const int lane = threadIdx.x & 63;
    const int w    = threadIdx.x >> 6;
    const int mg   = w & 1;             // edge-group
    const int kh   = w >> 1;            // k-half
    const int lo5  = lane & 31;
    const int hi   = lane >> 5;
    const int e0   = blockIdx.x * 128 + mg * 64;
    const int kb   = kh * 64;

    const int rc0 = min(e0 + lo5, NE - 1);
    const int rc1 = min(e0 + 32 + lo5, NE - 1);
    const int s0 = srcS[rc0];
    const int s1 = srcS[rc1];

    // x fragments resident as f32 (no unpack in hot loop)
    float xr0[PH][8], xr1[PH][8];
    {
        const float* xb0 = xi + (size_t)s0 * XS + hi * 8;
        const float* xb1 = xi + (size_t)s1 * XS + hi * 8;
#pragma unroll
        for (int p = 0; p < PH; ++p) {
            float4 a = *reinterpret_cast<const float4*>(xb0 + p * 16);
            float4 b = *reinterpret_cast<const float4*>(xb0 + p * 16 + 4);
            xr0[p][0] = a.x; xr0[p][1] = a.y; xr0[p][2] = a.z; xr0[p][3] = a.w;
            xr0[p][4] = b.x; xr0[p][5] = b.y; xr0[p][6] = b.z; xr0[p][7] = b.w;
            float4 c = *reinterpret_cast<const float4*>(xb1 + p * 16);
            float4 d = *reinterpret_cast<const float4*>(xb1 + p * 16 + 4);
            xr1[p][0] = c.x; xr1[p][1] = c.y; xr1[p][2] = c.z; xr1[p][3] = c.w;
            xr1[p][4] = d.x; xr1[p][5] = d.y; xr1[p][6] = d.z; xr1[p][7] = d.w;
        }
    }

    f32x16 acc[2][NT];
#pragma unroll
    for (int m = 0; m < 2; ++m)
#pragma unroll
        for (int n = 0; n < NT; ++n)
#pragma unroll
            for (int i = 0; i < 16; ++i) acc[m][n][i] = 0.f;

    // stage one 16KB chunk for this k-half; the 2 waves of a k-half split the 16 items
    auto stage = [&](int buf, int kc) {
#pragma unroll
        for (int jj = 0; jj < 8; ++jj) {
            const int j  = mg + jj * 2;
            const int n  = j % NT;
            const int kp = j / NT;
            const int p  = kp % PH;
            const int kk = kp / PH;
            gload_lds16(w2t + (size_t)(n * 32 + lo5) * KP
                            + (size_t)(kb + kc + kk) * MI + p * 16 + hi * 8,
                        &sb[kh][buf][j * 512]);
        }
    };

    // h prefetch from TRANSPOSED hT: coalesced 2B/lane loads
    __bf16 hc0[CH], hc1[CH], hn0[CH], hn1[CH];

    stage(0, 0);
#pragma unroll
    for (int kk = 0; kk < CH; ++kk) {
        hc0[kk] = hT[(size_t)(kb + kk) * NE + rc0];
        hc1[kk] = hT[(size_t)(kb + kk) * NE + rc1];
    }

    for (int c = 0; c < NCH; ++c) {
        const bool pf = (c + 1 < NCH);
        if (pf) {
            stage((c + 1) & 1, (c + 1) * CH);
#pragma unroll
            for (int kk = 0; kk < CH; ++kk) {
                hn0[kk] = hT[(size_t)(kb + (c + 1) * CH + kk) * NE + rc0];
                hn1[kk] = hT[(size_t)(kb + (c + 1) * CH + kk) * NE + rc1];
            }
        }
        // barrier #1: chunk-c data ready (counted wait keeps prefetch in flight)
        if (pf) VmWait<VMK>::run(); else VmWait<0>::run();
        __builtin_amdgcn_s_barrier();
        __builtin_amdgcn_sched_barrier(0);
        asm volatile("" ::: "memory");

        const __bf16* sbc = &sb[kh][c & 1][0];
#pragma unroll
        for (int p = 0; p < PH; ++p) {
#pragma unroll
            for (int kk = 0; kk < CH; ++kk) {
                const float hv0 = (float)hc0[kk];
                const float hv1 = (float)hc1[kk];
                bf16x8 af0, af1;
#pragma unroll
                for (int j = 0; j < 8; ++j) {
                    af0[j] = (__bf16)(hv0 * xr0[p][j]);
                    af1[j] = (__bf16)(hv1 * xr1[p][j]);
                }
#pragma unroll
                for (int n = 0; n < NT; ++n) {
                    const bf16x8 bv = *reinterpret_cast<const bf16x8*>(
                        &sbc[((kk * PH + p) * NT + n) * 512 + lane * 8]);
                    acc[0][n] = __builtin_amdgcn_mfma_f32_32x32x16_bf16(af0, bv, acc[0][n], 0, 0, 0);
                    acc[1][n] = __builtin_amdgcn_mfma_f32_32x32x16_bf16(af1, bv, acc[1][n], 0, 0, 0);
                }
            }
        }
        // barrier #2: all waves done reading buf[c&1] before next iter overwrites it
        __builtin_amdgcn_sched_barrier(0);
        asm volatile("" ::: "memory");
        __builtin_amdgcn_s_barrier();
        if (pf) {
#pragma unroll
            for (int kk = 0; kk < CH; ++kk) { hc0[kk] = hn0[kk]; hc1[kk] = hn1[kk]; }
        }
    }

    // k == 128 tail (folded b2 term, hfac = 1) — kh==1 only, direct global B
    if (kh == 1) {
#pragma unroll
        for (int p = 0; p < PH; ++p) {
            bf16x8 af0, af1;
#pragma unroll
            for (int j = 0; j < 8; ++j) {
                af0[j] = (__bf16)xr0[p][j];
                af1[j] = (__bf16)xr1[p][j];
            }
#pragma unroll
            for (int n = 0; n < NT; ++n) {
                const bf16x8 bv = *reinterpret_cast<const bf16x8*>(
                    w2t + (size_t)(n * 32 + lo5) * KP + (size_t)128 * MI + p * 16 + hi * 8);
                acc[0][n] = __builtin_amdgcn_mfma_f32_32x32x16_bf16(af0, bv, acc[0][n], 0, 0, 0);
                acc[1][n] = __builtin_amdgcn_mfma_f32_32x32x16_bf16(af1, bv, acc[1][n], 0, 0, 0);
            }
        }
    }

    // ---- merge k-halves via LDS (reuse sb; stride-17 scalar layout = conflict-free) ----
    __syncthreads();                        // full drain; sb free
    float* red = reinterpret_cast<float*>(&sb[0][0][0]);
    if (kh == 1) {
#pragma unroll
        for (int m = 0; m < 2; ++m)
#pragma unroll
            for (int n = 0; n < NT; ++n) {
                float* dst = red + (size_t)(((mg * 2 + m) * NT + n) * 64 + lane) * 17;
#pragma unroll
                for (int i = 0; i < 16; ++i) dst[i] = acc[m][n][i];
            }
    }
    __syncthreads();
    if (kh == 0) {
#pragma unroll
        for (int m = 0; m < 2; ++m)
#pragma unroll
            for (int n = 0; n < NT; ++n) {
                const float* s = red + (size_t)(((mg * 2 + m) * NT + n) * 64 + lane) * 17;
#pragma unroll
                for (int i = 0; i < 16; ++i) acc[m][n][i] += s[i];
            }
        // store: C layout col = lane&31, row = (reg&3) + 8*(reg>>2) + 4*(lane>>5)
#pragma unroll
        for (int m = 0; m < 2; ++m)
#pragma unroll
            for (int q = 0; q < 4; ++q)
#pragma unroll
                for (int a = 0; a < 4; ++a) {
                    const int e = e0 + m * 32 + 4 * hi + 8 * q + a;
                    if (e < NE) {
#pragma unroll
                        for (int n = 0; n < NT; ++n)
                            msg[(size_t)e * MO + n * 32 + lo5] = acc[m][n][4 * q + a];
                    }
                }
    }
}

// ---------------- agg: out[n,o] = elu( bias[o] + xi@root + sum_{j in CSR[n]} msg[j,o] ) ----------------
template <int MI, int MO, int XS>
__global__ void k_agg(const float* __restrict__ msg, const int* __restrict__ rowptr,
                      const float* __restrict__ xi, const float* __restrict__ root,
                      const float* __restrict__ bias, float* __restrict__ out) {
    int idx = blockIdx.x * 256 + threadIdx.x;
    if (idx >= NN * MO) return;
    int n = idx / MO, o = idx % MO;
    float s = bias[o];
#pragma unroll
    for (int i = 0; i < MI; ++i) s = fmaf(xi[(size_t)n * XS + i], root[i * MO + o], s);
    const int j0 = rowptr[n], j1 = rowptr[n + 1];
    for (int j = j0; j < j1; ++j) s += msg[(size_t)j * MO + o];
    out[idx] = eluf(s);
}

// ---------------- pool nodes -> subgraphs (sum + count) ----------------
__global__ void k_pool_s(const float* __restrict__ xi, const float* __restrict__ x,
                         const int* __restrict__ n2s, float* __restrict__ xs_sum,
                         float* __restrict__ cs) {
    int idx = blockIdx.x * 256 + threadIdx.x;
    if (idx >= NN * 72) return;
    int n = idx / 72, j = idx % 72;
    float v = (j < 64) ? xi[n * 64 + j] : x[n * 24 + 16 + (j - 64)];
    int s = n2s[n];
    atomicAdd(&xs_sum[s * 72 + j], v);
    if (j == 0) atomicAdd(&cs[s], 1.f);
}

// ---------------- pool subgraphs -> graphs (mean of means) ----------------
__global__ void k_pool_g(const float* __restrict__ xs_sum, const float* __restrict__ cs,
                         const int* __restrict__ s2g, float* __restrict__ xg_sum,
                         float* __restrict__ cg) {
    int idx = blockIdx.x * 256 + threadIdx.x;
    if (idx >= NS * 72) return;
    int s = idx / 72, j = idx % 72;
    float v = xs_sum[s * 72 + j] / fmaxf(cs[s], 1.f);
    int g = s2g[s];
    atomicAdd(&xg_sum[g * 72 + j], v);
    if (j == 0) atomicAdd(&cg[g], 1.f);
}

// ---------------- final MLP: 72 -> 36 -> 18 -> 1 ----------------
__global__ void k_fc(const float* __restrict__ xg_sum, const float* __restrict__ cg,
                     const float* __restrict__ w1, const float* __restrict__ b1,
                     const float* __restrict__ w2, const float* __restrict__ b2,
                     const float* __restrict__ w3, const float* __restrict__ b3,
                     float* __restrict__ out) {
    int g = threadIdx.x;
    if (g >= NG) return;
    float inv = 1.f / fmaxf(cg[g], 1.f);
    float v[72];
#pragma unroll
    for (int j = 0; j < 72; ++j) v[j] = xg_sum[g * 72 + j] * inv;
    float h1[36];
#pragma unroll
    for (int o = 0; o < 36; ++o) {
        float s = b1[o];
#pragma unroll
        for (int i = 0; i < 72; ++i) s = fmaf(v[i], w1[i * 36 + o], s);
        h1[o] = eluf(s);
    }
    float h2[18];
#pragma unroll
    for (int o = 0; o < 18; ++o) {
        float s = b2[o];
#pragma unroll
        for (int i = 0; i < 36; ++i) s = fmaf(h1[i], w2[i * 18 + o], s);
        h2[o] = eluf(s);
    }
    float s = b3[0];
#pragma unroll
    for (int i = 0; i < 18; ++i) s = fmaf(h2[i], w3[i], s);
    out[g] = s;
}

// ---------------- launcher ----------------
extern "C" void kernel_launch(void* const* d_in, const int* in_sizes, int n_in,
                              void* d_out, int out_size, void* d_ws, size_t ws_size,
                              hipStream_t stream) {
    const float* x   = (const float*)d_in[0];
    const int*   ei  = (const int*)d_in[1];
    const float* ea  = (const float*)d_in[2];
    const int*   n2s = (const int*)d_in[3];
    const int*   s2g = (const int*)d_in[4];
    const int* src = ei;
    const int* dst = ei + NE;

    const float* cw1[3]   = {(const float*)d_in[5],  (const float*)d_in[11], (const float*)d_in[17]};
    const float* cb1[3]   = {(const float*)d_in[6],  (const float*)d_in[12], (const float*)d_in[18]};
    const float* cw2[3]   = {(const float*)d_in[7],  (const float*)d_in[13], (const float*)d_in[19]};
    const float* cb2[3]   = {(const float*)d_in[8],  (const float*)d_in[14], (const float*)d_in[20]};
    const float* croot[3] = {(const float*)d_in[9],  (const float*)d_in[15], (const float*)d_in[21]};
    const float* cbias[3] = {(const float*)d_in[10], (const float*)d_in[16], (const float*)d_in[22]};
    const float* fc1w = (const float*)d_in[23];
    const float* fc1b = (const float*)d_in[24];
    const float* fc2w = (const float*)d_in[25];
    const float* fc2b = (const float*)d_in[26];
    const float* fc3w = (const float*)d_in[27];
    const float* fc3b = (const float*)d_in[28];

    // ---- workspace layout (bytes, 16-aligned) ----
    char* W = (char*)d_ws;
    __bf16* hT    = (__bf16*)(W);                   // 128*NE*2   = 15,360,000
    float*  xiA   = (float*)(W + 15360000);         // NN*64*4    =  5,120,000
    float*  xiB   = (float*)(W + 20480000);         // NN*64*4    =  5,120,000
    float*  msg   = (float*)(W + 25600000);         // NE*64*4    = 15,360,000
    float*  xs_sum= (float*)(W + 40960000);         // NS*72*4    =    864,000
    float*  cs    = (float*)(W + 41824000);         // NS*4       =     12,000
    float*  xg_sum= (float*)(W + 41836000);         // NG*72*4    =     36,864
    float*  cg    = (float*)(W + 41872864);         // NG*4       =        512
    __bf16* w2t0  = (__bf16*)(W + 41873376);        // 32*2064*2  =    132,096
    __bf16* w2t1  = (__bf16*)(W + 42005472);        // 64*4128*2  =    528,384
    __bf16* w2t2  = (__bf16*)(W + 42533856);        // 64*8256*2  =  1,056,768
    int*    deg   = (int*)(W + 43590624);           // NN*4       =     80,000
    int*    tmp   = (int*)(W + 43670624);           // NN*4       =     80,000
    int*    rowptr= (int*)(W + 43750624);           // (NN+1)*4   ->    80,016
    int*    eord  = (int*)(W + 43830640);           // NE*4       =    240,000
    int*    srcS  = (int*)(W + 44070640);           // NE*4       =    240,000
    int*    bsum  = (int*)(W + 44310640);           // SCB*4      =        316
    int*    boff  = (int*)(W + 44310960);           // SCB*4      =        316
    // total ~44,311,276 bytes

    // zero: pooling accumulators + sort counters
    hipMemsetAsync(xs_sum, 0, (size_t)(NS * 72 + NS) * 4 + (size_t)(NG * 72 + NG) * 4, stream);
    hipMemsetAsync(deg, 0, 160000, stream);

    // ---- one-time edge sort by dst (hierarchical scan) ----
    k_hist<<<(NE + 255) / 256, 256, 0, stream>>>(dst, deg);
    k_scan1<<<SCB, 256, 0, stream>>>(deg, bsum);
    k_scan2<<<1, 128, 0, stream>>>(bsum, boff);
    k_scan3<<<SCB, 256, 0, stream>>>(deg, boff, rowptr);
    k_scatter<<<(NE + 255) / 256, 256, 0, stream>>>(src, dst, rowptr, tmp, eord, srcS);

    // prep: transposed bf16 W2 (with b2 folded as k==128)
    k_w2t<16, 32><<<(32 * 129 * 16 + 255) / 256, 256, 0, stream>>>(cw2[0], cb2[0], w2t0);
    k_w2t<32, 64><<<(64 * 129 * 32 + 255) / 256, 256, 0, stream>>>(cw2[1], cb2[1], w2t1);
    k_w2t<64, 64><<<(64 * 129 * 64 + 255) / 256, 256, 0, stream>>>(cw2[2], cb2[2], w2t2);

    const int EB3 = (NE + 127) / 128;   // 469 blocks of 4 waves
    const int HB  = (NE * HIDN + 255) / 256;

    // ---- layer 0: MI=16, MO=32, x (stride 24) -> xiB ----
    k_hT<<<HB, 256, 0, stream>>>(eord, ea, cw1[0], cb1[0], hT);
    k_edge4<16, 32, 24><<<EB3, 256, 0, stream>>>(x, hT, w2t0, srcS, msg);
    k_agg<16, 32, 24><<<(NN * 32 + 255) / 256, 256, 0, stream>>>(msg, rowptr, x, croot[0], cbias[0], xiB);

    // ---- layer 1: MI=32, MO=64, xiB -> xiA ----
    k_hT<<<HB, 256, 0, stream>>>(eord, ea, cw1[1], cb1[1], hT);
    k_edge4<32, 64, 32><<<EB3, 256, 0, stream>>>(xiB, hT, w2t1, srcS, msg);
    k_agg<32, 64, 32><<<(NN * 64 + 255) / 256, 256, 0, stream>>>(msg, rowptr, xiB, croot[1], cbias[1], xiA);

    // ---- layer 2: MI=64, MO=64, xiA -> xiB ----
    k_hT<<<HB, 256, 0, stream>>>(eord, ea, cw1[2], cb1[2], hT);
    k_edge4<64, 64, 64><<<EB3, 256, 0, stream>>>(xiA, hT, w2t2, srcS, msg);
    k_agg<64, 64, 64><<<(NN * 64 + 255) / 256, 256, 0, stream>>>(msg, rowptr, xiA, croot[2], cbias[2], xiB);

    // ---- pooling + MLP ----
    k_pool_s<<<(NN * 72 + 255) / 256, 256, 0, stream>>>(xiB, x, n2s, xs_sum, cs);
    k_pool_g<<<(NS * 72 + 255) / 256, 256, 0, stream>>>(xs_sum, cs, s2g, xg_sum, cg);
    k_fc<<<1, 128, 0, stream>>>(xg_sum, cg, fc1w, fc1b, fc2w, fc2b, fc3w, fc3b, (float*)d_out);
}

// Round 10
// 397.918 us; speedup vs baseline: 1.0165x; 1.0165x over previous
//
#include <hip/hip_runtime.h>
#include <hip/hip_bf16.h>
#include <cmath>

#define NN 20000   // nodes
#define NE 60000   // edges
#define NS 3000    // subgraphs
#define NG 128     // graphs
#define HIDN 128   // hidden dim of edge-attr MLP
#define SCB 79     // scan blocks = ceil(NN/256)

typedef float f32x16 __attribute__((ext_vector_type(16)));
typedef __bf16 bf16x8 __attribute__((ext_vector_type(8)));

__device__ __forceinline__ float eluf(float v) { return v > 0.f ? v : expm1f(v); }

// async global->LDS, 16B per lane; lds ptr must be wave-uniform (HW writes base + lane*16)
__device__ __forceinline__ void gload_lds16(const void* g, void* l) {
    __builtin_amdgcn_global_load_lds(
        (const __attribute__((address_space(1))) unsigned int*)g,
        (__attribute__((address_space(3))) unsigned int*)l, 16, 0, 0);
}

// counted vmcnt waits (literal immediates required in asm)
template <int N> struct VmWait;
template <> struct VmWait<0>  { static __device__ __forceinline__ void run() { asm volatile("s_waitcnt vmcnt(0)"  ::: "memory"); } };
template <> struct VmWait<6>  { static __device__ __forceinline__ void run() { asm volatile("s_waitcnt vmcnt(6)"  ::: "memory"); } };
template <> struct VmWait<8>  { static __device__ __forceinline__ void run() { asm volatile("s_waitcnt vmcnt(8)"  ::: "memory"); } };
template <> struct VmWait<20> { static __device__ __forceinline__ void run() { asm volatile("s_waitcnt vmcnt(20)" ::: "memory"); } };

// ================= one-time edge sort by dst (counting sort) =================
__global__ void k_hist(const int* __restrict__ dst, int* __restrict__ deg) {
    int e = blockIdx.x * 256 + threadIdx.x;
    if (e < NE) atomicAdd(&deg[dst[e]], 1);
}

__global__ void k_scan1(const int* __restrict__ deg, int* __restrict__ bsum) {
    __shared__ int s[256];
    const int t = threadIdx.x;
    int i = blockIdx.x * 256 + t;
    s[t] = (i < NN) ? deg[i] : 0;
    __syncthreads();
#pragma unroll
    for (int off = 128; off > 0; off >>= 1) {
        if (t < off) s[t] += s[t + off];
        __syncthreads();
    }
    if (t == 0) bsum[blockIdx.x] = s[0];
}

__global__ void k_scan2(const int* __restrict__ bsum, int* __restrict__ boff) {
    __shared__ int s[SCB];
    const int t = threadIdx.x;
    if (t < SCB) s[t] = bsum[t];
    __syncthreads();
    if (t == 0) {
        int acc = 0;
        for (int i = 0; i < SCB; ++i) { int v = s[i]; s[i] = acc; acc += v; }
    }
    __syncthreads();
    if (t < SCB) boff[t] = s[t];
}

__global__ void k_scan3(const int* __restrict__ deg, const int* __restrict__ boff,
                        int* __restrict__ rowptr) {
    __shared__ int s[256];
    const int t = threadIdx.x;
    int i = blockIdx.x * 256 + t;
    int v = (i < NN) ? deg[i] : 0;
    s[t] = v;
    __syncthreads();
#pragma unroll
    for (int off = 1; off < 256; off <<= 1) {
        int a = (t >= off) ? s[t - off] : 0;
        __syncthreads();
        s[t] += a;
        __syncthreads();
    }
    if (i < NN) rowptr[i + 1] = boff[blockIdx.x] + s[t];
    if (i == 0) rowptr[0] = 0;
}

__global__ void k_scatter(const int* __restrict__ src, const int* __restrict__ dst,
                          const int* __restrict__ rowptr, int* __restrict__ tmp,
                          int* __restrict__ eord, int* __restrict__ srcS) {
    int e = blockIdx.x * 256 + threadIdx.x;
    if (e >= NE) return;
    int d = dst[e];
    int pos = rowptr[d] + atomicAdd(&tmp[d], 1);
    eord[pos] = e;
    srcS[pos] = src[e];
}

// ---------------- hT[j][es] = relu(ea[eord[es]] @ w1 + b1)  (128 x E bf16, transposed) --------
// e-tile-major: ea rows staged in LDS; wave-uniform j -> scalar w1/b1 loads; coalesced hT writes.
__global__ void k_hT2(const int* __restrict__ eord, const float* __restrict__ ea,
                      const float* __restrict__ w1, const float* __restrict__ b1,
                      __bf16* __restrict__ hT) {
    __shared__ float sea[64][5];
    const int t  = threadIdx.x;
    const int eb = blockIdx.x * 64;
    for (int i = t; i < 320; i += 256) {
        int el = i / 5, d = i % 5;
        int es = eb + el;
        int e = (es < NE) ? eord[es] : 0;
        sea[el][d] = ea[e * 5 + d];
    }
    __syncthreads();
    const int w = t >> 6, lane = t & 63;
    const int es = eb + lane;
    const float a0 = sea[lane][0], a1 = sea[lane][1], a2 = sea[lane][2],
                a3 = sea[lane][3], a4 = sea[lane][4];
#pragma unroll 4
    for (int jj = 0; jj < 32; ++jj) {
        const int j = w * 32 + jj;
        float s = b1[j];
        s = fmaf(a0, w1[0 * HIDN + j], s);
        s = fmaf(a1, w1[1 * HIDN + j], s);
        s = fmaf(a2, w1[2 * HIDN + j], s);
        s = fmaf(a3, w1[3 * HIDN + j], s);
        s = fmaf(a4, w1[4 * HIDN + j], s);
        if (es < NE) hT[(size_t)j * NE + es] = (__bf16)fmaxf(s, 0.f);
    }
}

// ---------------- w2t[o][kg] = bf16( kg<128*MI ? w2[kg*MO+o] : b2[(kg-128MI)*MO+o] ) ----------------
template <int MI, int MO>
__global__ void k_w2t(const float* __restrict__ w2, const float* __restrict__ b2,
                      __bf16* __restrict__ w2t) {
    constexpr int KP = 129 * MI;
    constexpr int KF = 128 * MI;
    int idx = blockIdx.x * 256 + threadIdx.x;
    if (idx >= MO * KP) return;
    int o = idx / KP, kg = idx % KP;
    float v = (kg < KF) ? w2[(size_t)kg * MO + o] : b2[(kg - KF) * MO + o];
    w2t[idx] = (__bf16)v;
}

// ---------------- MFMA edge kernel: quarter-K waves, counted-vmcnt pipeline ----------------
// Block = 4 waves (mg x kh): wave = 64 edges x full MO x K-quarter (32 k).
// blockIdx.y picks outer K-half -> msgA/msgB (disjoint buffers, merged in k_agg).
// In-block kh pair merged via LDS. B chunks (8KB) shared by the 2 mg waves, double-buffered.
template <int MI, int MO, int XS>
__global__ __launch_bounds__(256, 3) void k_edge5(
    const float* __restrict__ xi, const __bf16* __restrict__ hT,
    const __bf16* __restrict__ w2t, const int* __restrict__ srcS,
    float* __restrict__ msgA, float* __restrict__ msgB) {
    constexpr int PH  = MI / 16;        // K-steps per k value
    constexpr int KP  = 129 * MI;       // w2t row length
    constexpr int NT  = MO / 32;        // N tiles
    constexpr int CH  = 8 / (PH * NT);  // k values per 8-item chunk
    constexpr int NCH = 32 / CH;        // chunks per K-quarter
    constexpr int VMK = 4 + 2 * CH;     // per-wave loads per iteration (4 stage + 2*CH h)
    static_assert(CH * PH * NT == 8, "ITEMS must be 8");

    __shared__ __align__(16) __bf16 sb[2][2][8 * 512];   // [kh][dbuf][8KB] = 32KB

    const int lane = threadIdx.x & 63;
    const int w    = threadIdx.x >> 6;
    const int mg   = w & 1;             // edge-group
    const int kh   = w >> 1;            // inner K split
    const int lo5  = lane & 31;
    const int hi   = lane >> 5;
    const int e0   = blockIdx.x * 128 + mg * 64;
    const int kb   = (2 * (int)blockIdx.y + kh) * 32;   // this wave's K-quarter base

    const int rc0 = min(e0 + lo5, NE - 1);
    const int rc1 = min(e0 + 32 + lo5, NE - 1);
    const int s0 = srcS[rc0];
    const int s1 = srcS[rc1];

    // x fragments resident as f32
    float xr0[PH][8], xr1[PH][8];
    {
        const float* xb0 = xi + (size_t)s0 * XS + hi * 8;
        const float* xb1 = xi + (size_t)s1 * XS + hi * 8;
#pragma unroll
        for (int p = 0; p < PH; ++p) {
            float4 a = *reinterpret_cast<const float4*>(xb0 + p * 16);
            float4 b = *reinterpret_cast<const float4*>(xb0 + p * 16 + 4);
            xr0[p][0] = a.x; xr0[p][1] = a.y; xr0[p][2] = a.z; xr0[p][3] = a.w;
            xr0[p][4] = b.x; xr0[p][5] = b.y; xr0[p][6] = b.z; xr0[p][7] = b.w;
            float4 c = *reinterpret_cast<const float4*>(xb1 + p * 16);
            float4 d = *reinterpret_cast<const float4*>(xb1 + p * 16 + 4);
            xr1[p][0] = c.x; xr1[p][1] = c.y; xr1[p][2] = c.z; xr1[p][3] = c.w;
            xr1[p][4] = d.x; xr1[p][5] = d.y; xr1[p][6] = d.z; xr1[p][7] = d.w;
        }
    }

    f32x16 acc[2][NT];
#pragma unroll
    for (int m = 0; m < 2; ++m)
#pragma unroll
        for (int n = 0; n < NT; ++n)
#pragma unroll
            for (int i = 0; i < 16; ++i) acc[m][n][i] = 0.f;

    // stage one 8KB chunk for this kh; the 2 mg waves split the 8 items
    auto stage = [&](int buf, int kc) {
#pragma unroll
        for (int jj = 0; jj < 4; ++jj) {
            const int j  = mg + jj * 2;
            const int n  = j % NT;
            const int kp = j / NT;
            const int p  = kp % PH;
            const int kk = kp / PH;
            gload_lds16(w2t + (size_t)(n * 32 + lo5) * KP
                            + (size_t)(kb + kc + kk) * MI + p * 16 + hi * 8,
                        &sb[kh][buf][j * 512]);
        }
    };

    __bf16 hc0[CH], hc1[CH], hn0[CH], hn1[CH];

    stage(0, 0);
#pragma unroll
    for (int kk = 0; kk < CH; ++kk) {
        hc0[kk] = hT[(size_t)(kb + kk) * NE + rc0];
        hc1[kk] = hT[(size_t)(kb + kk) * NE + rc1];
    }

    for (int c = 0; c < NCH; ++c) {
        const bool pf = (c + 1 < NCH);
        if (pf) {
            stage((c + 1) & 1, (c + 1) * CH);
#pragma unroll
            for (int kk = 0; kk < CH; ++kk) {
                hn0[kk] = hT[(size_t)(kb + (c + 1) * CH + kk) * NE + rc0];
                hn1[kk] = hT[(size_t)(kb + (c + 1) * CH + kk) * NE + rc1];
            }
        }
        if (pf) VmWait<VMK>::run(); else VmWait<0>::run();
        __builtin_amdgcn_s_barrier();
        __builtin_amdgcn_sched_barrier(0);
        asm volatile("" ::: "memory");

        const __bf16* sbc = &sb[kh][c & 1][0];
#pragma unroll
        for (int p = 0; p < PH; ++p) {
#pragma unroll
            for (int kk = 0; kk < CH; ++kk) {
                const float hv0 = (float)hc0[kk];
                const float hv1 = (float)hc1[kk];
                bf16x8 af0, af1;
#pragma unroll
                for (int j = 0; j < 8; ++j) {
                    af0[j] = (__bf16)(hv0 * xr0[p][j]);
                    af1[j] = (__bf16)(hv1 * xr1[p][j]);
                }
#pragma unroll
                for (int n = 0; n < NT; ++n) {
                    const bf16x8 bv = *reinterpret_cast<const bf16x8*>(
                        &sbc[((kk * PH + p) * NT + n) * 512 + lane * 8]);
                    acc[0][n] = __builtin_amdgcn_mfma_f32_32x32x16_bf16(af0, bv, acc[0][n], 0, 0, 0);
                    acc[1][n] = __builtin_amdgcn_mfma_f32_32x32x16_bf16(af1, bv, acc[1][n], 0, 0, 0);
                }
            }
        }
        __builtin_amdgcn_sched_barrier(0);
        asm volatile("" ::: "memory");
        __builtin_amdgcn_s_barrier();
        if (pf) {
#pragma unroll
            for (int kk = 0; kk < CH; ++kk) { hc0[kk] = hn0[kk]; hc1[kk] = hn1[kk]; }
        }
    }

    // k == 128 tail (folded b2, hfac = 1): last K-quarter only, direct global B
    if (blockIdx.y == 1 && kh == 1) {
#pragma unroll
        for (int p = 0; p < PH; ++p) {
            bf16x8 af0, af1;
#pragma unroll
            for (int j = 0; j < 8; ++j) {
                af0[j] = (__bf16)xr0[p][j];
                af1[j] = (__bf16)xr1[p][j];
            }
#pragma unroll
            for (int n = 0; n < NT; ++n) {
                const bf16x8 bv = *reinterpret_cast<const bf16x8*>(
                    w2t + (size_t)(n * 32 + lo5) * KP + (size_t)128 * MI + p * 16 + hi * 8);
                acc[0][n] = __builtin_amdgcn_mfma_f32_32x32x16_bf16(af0, bv, acc[0][n], 0, 0, 0);
                acc[1][n] = __builtin_amdgcn_mfma_f32_32x32x16_bf16(af1, bv, acc[1][n], 0, 0, 0);
            }
        }
    }

    // ---- merge kh pair via LDS: layout red[tile][i][lane] -> conflict-free scalar ops ----
    __syncthreads();
    float* red = reinterpret_cast<float*>(&sb[0][0][0]);   // 8*NT/2... tiles*(16*64) f32 <= 32KB
    if (kh == 1) {
#pragma unroll
        for (int m = 0; m < 2; ++m)
#pragma unroll
            for (int n = 0; n < NT; ++n) {
                float* d = red + (size_t)((mg * 2 + m) * NT + n) * 1024 + lane;
#pragma unroll
                for (int i = 0; i < 16; ++i) d[i * 64] = acc[m][n][i];
            }
    }
    __syncthreads();
    if (kh == 0) {
        float* mout = (blockIdx.y == 0) ? msgA : msgB;
#pragma unroll
        for (int m = 0; m < 2; ++m)
#pragma unroll
            for (int n = 0; n < NT; ++n) {
                const float* s = red + (size_t)((mg * 2 + m) * NT + n) * 1024 + lane;
#pragma unroll
                for (int i = 0; i < 16; ++i) acc[m][n][i] += s[i * 64];
            }
        // store: C layout col = lane&31, row = (reg&3) + 8*(reg>>2) + 4*(lane>>5)
#pragma unroll
        for (int m = 0; m < 2; ++m)
#pragma unroll
            for (int q = 0; q < 4; ++q)
#pragma unroll
                for (int a = 0; a < 4; ++a) {
                    const int e = e0 + m * 32 + 4 * hi + 8 * q + a;
                    if (e < NE) {
#pragma unroll
                        for (int n = 0; n < NT; ++n)
                            mout[(size_t)e * MO + n * 32 + lo5] = acc[m][n][4 * q + a];
                    }
                }
    }
}

// ---------------- agg: out[n,o] = elu( bias[o] + xi@root + sum_{j in CSR[n]} (msgA+msgB)[j,o] ) ----
template <int MI, int MO, int XS>
__global__ void k_agg(const float* __restrict__ msgA, const float* __restrict__ msgB,
                      const int* __restrict__ rowptr,
                      const float* __restrict__ xi, const float* __restrict__ root,
                      const float* __restrict__ bias, float* __restrict__ out) {
    int idx = blockIdx.x * 256 + threadIdx.x;
    if (idx >= NN * MO) return;
    int n = idx / MO, o = idx % MO;
    float s = bias[o];
#pragma unroll
    for (int i = 0; i < MI; ++i) s = fmaf(xi[(size_t)n * XS + i], root[i * MO + o], s);
    const int j0 = rowptr[n], j1 = rowptr[n + 1];
    for (int j = j0; j < j1; ++j)
        s += msgA[(size_t)j * MO + o] + msgB[(size_t)j * MO + o];
    out[idx] = eluf(s);
}

// ---------------- pool nodes -> subgraphs (sum + count) ----------------
__global__ void k_pool_s(const float* __restrict__ xi, const float* __restrict__ x,
                         const int* __restrict__ n2s, float* __restrict__ xs_sum,
                         float* __restrict__ cs) {
    int idx = blockIdx.x * 256 + threadIdx.x;
    if (idx >= NN * 72) return;
    int n = idx / 72, j = idx % 72;
    float v = (j < 64) ? xi[n * 64 + j] : x[n * 24 + 16 + (j - 64)];
    int s = n2s[n];
    atomicAdd(&xs_sum[s * 72 + j], v);
    if (j == 0) atomicAdd(&cs[s], 1.f);
}

// ---------------- pool subgraphs -> graphs (mean of means) ----------------
__global__ void k_pool_g(const float* __restrict__ xs_sum, const float* __restrict__ cs,
                         const int* __restrict__ s2g, float* __restrict__ xg_sum,
                         float* __restrict__ cg) {
    int idx = blockIdx.x * 256 + threadIdx.x;
    if (idx >= NS * 72) return;
    int s = idx / 72, j = idx % 72;
    float v = xs_sum[s * 72 + j] / fmaxf(cs[s], 1.f);
    int g = s2g[s];
    atomicAdd(&xg_sum[g * 72 + j], v);
    if (j == 0) atomicAdd(&cg[g], 1.f);
}

// ---------------- final MLP: 72 -> 36 -> 18 -> 1 ----------------
__global__ void k_fc(const float* __restrict__ xg_sum, const float* __restrict__ cg,
                     const float* __restrict__ w1, const float* __restrict__ b1,
                     const float* __restrict__ w2, const float* __restrict__ b2,
                     const float* __restrict__ w3, const float* __restrict__ b3,
                     float* __restrict__ out) {
    int g = threadIdx.x;
    if (g >= NG) return;
    float inv = 1.f / fmaxf(cg[g], 1.f);
    float v[72];
#pragma unroll
    for (int j = 0; j < 72; ++j) v[j] = xg_sum[g * 72 + j] * inv;
    float h1[36];
#pragma unroll
    for (int o = 0; o < 36; ++o) {
        float s = b1[o];
#pragma unroll
        for (int i = 0; i < 72; ++i) s = fmaf(v[i], w1[i * 36 + o], s);
        h1[o] = eluf(s);
    }
    float h2[18];
#pragma unroll
    for (int o = 0; o < 18; ++o) {
        float s = b2[o];
#pragma unroll
        for (int i = 0; i < 36; ++i) s = fmaf(h1[i], w2[i * 18 + o], s);
        h2[o] = eluf(s);
    }
    float s = b3[0];
#pragma unroll
    for (int i = 0; i < 18; ++i) s = fmaf(h2[i], w3[i], s);
    out[g] = s;
}

// ---------------- launcher ----------------
extern "C" void kernel_launch(void* const* d_in, const int* in_sizes, int n_in,
                              void* d_out, int out_size, void* d_ws, size_t ws_size,
                              hipStream_t stream) {
    const float* x   = (const float*)d_in[0];
    const int*   ei  = (const int*)d_in[1];
    const float* ea  = (const float*)d_in[2];
    const int*   n2s = (const int*)d_in[3];
    const int*   s2g = (const int*)d_in[4];
    const int* src = ei;
    const int* dst = ei + NE;

    const float* cw1[3]   = {(const float*)d_in[5],  (const float*)d_in[11], (const float*)d_in[17]};
    const float* cb1[3]   = {(const float*)d_in[6],  (const float*)d_in[12], (const float*)d_in[18]};
    const float* cw2[3]   = {(const float*)d_in[7],  (const float*)d_in[13], (const float*)d_in[19]};
    const float* cb2[3]   = {(const float*)d_in[8],  (const float*)d_in[14], (const float*)d_in[20]};
    const float* croot[3] = {(const float*)d_in[9],  (const float*)d_in[15], (const float*)d_in[21]};
    const float* cbias[3] = {(const float*)d_in[10], (const float*)d_in[16], (const float*)d_in[22]};
    const float* fc1w = (const float*)d_in[23];
    const float* fc1b = (const float*)d_in[24];
    const float* fc2w = (const float*)d_in[25];
    const float* fc2b = (const float*)d_in[26];
    const float* fc3w = (const float*)d_in[27];
    const float* fc3b = (const float*)d_in[28];

    // ---- workspace layout (bytes, 16-aligned) ----
    char* W = (char*)d_ws;
    __bf16* hT    = (__bf16*)(W);                   // 128*NE*2   = 15,360,000
    float*  xiA   = (float*)(W + 15360000);         // NN*64*4    =  5,120,000
    float*  xiB   = (float*)(W + 20480000);         // NN*64*4    =  5,120,000
    float*  msgA  = (float*)(W + 25600000);         // NE*64*4    = 15,360,000
    float*  msgB  = (float*)(W + 40960000);         // NE*64*4    = 15,360,000
    float*  xs_sum= (float*)(W + 56320000);         // NS*72*4    =    864,000
    float*  cs    = (float*)(W + 57184000);         // NS*4       =     12,000
    float*  xg_sum= (float*)(W + 57196000);         // NG*72*4    =     36,864
    float*  cg    = (float*)(W + 57232864);         // NG*4       =        512
    __bf16* w2t0  = (__bf16*)(W + 57233376);        // 32*2064*2  =    132,096
    __bf16* w2t1  = (__bf16*)(W + 57365472);        // 64*4128*2  =    528,384
    __bf16* w2t2  = (__bf16*)(W + 57893856);        // 64*8256*2  =  1,056,768
    int*    deg   = (int*)(W + 58950624);           // NN*4       =     80,000
    int*    tmp   = (int*)(W + 59030624);           // NN*4       =     80,000
    int*    rowptr= (int*)(W + 59110624);           // (NN+1)*4   ->    80,016
    int*    eord  = (int*)(W + 59190640);           // NE*4       =    240,000
    int*    srcS  = (int*)(W + 59430640);           // NE*4       =    240,000
    int*    bsum  = (int*)(W + 59670640);           // SCB*4
    int*    boff  = (int*)(W + 59670960);           // SCB*4
    // total ~59,671,280 bytes

    // zero: pooling accumulators + sort counters
    hipMemsetAsync(xs_sum, 0, (size_t)(NS * 72 + NS) * 4 + (size_t)(NG * 72 + NG) * 4, stream);
    hipMemsetAsync(deg, 0, 160000, stream);

    // ---- one-time edge sort by dst (hierarchical scan) ----
    k_hist<<<(NE + 255) / 256, 256, 0, stream>>>(dst, deg);
    k_scan1<<<SCB, 256, 0, stream>>>(deg, bsum);
    k_scan2<<<1, 128, 0, stream>>>(bsum, boff);
    k_scan3<<<SCB, 256, 0, stream>>>(deg, boff, rowptr);
    k_scatter<<<(NE + 255) / 256, 256, 0, stream>>>(src, dst, rowptr, tmp, eord, srcS);

    // prep: transposed bf16 W2 (with b2 folded as k==128)
    k_w2t<16, 32><<<(32 * 129 * 16 + 255) / 256, 256, 0, stream>>>(cw2[0], cb2[0], w2t0);
    k_w2t<32, 64><<<(64 * 129 * 32 + 255) / 256, 256, 0, stream>>>(cw2[1], cb2[1], w2t1);
    k_w2t<64, 64><<<(64 * 129 * 64 + 255) / 256, 256, 0, stream>>>(cw2[2], cb2[2], w2t2);

    const int EB5 = (NE + 127) / 128;   // 469
    const int HTB = (NE + 63) / 64;     // 938

    // ---- layer 0: MI=16, MO=32, x (stride 24) -> xiB ----
    k_hT2<<<HTB, 256, 0, stream>>>(eord, ea, cw1[0], cb1[0], hT);
    k_edge5<16, 32, 24><<<dim3(EB5, 2), 256, 0, stream>>>(x, hT, w2t0, srcS, msgA, msgB);
    k_agg<16, 32, 24><<<(NN * 32 + 255) / 256, 256, 0, stream>>>(msgA, msgB, rowptr, x, croot[0], cbias[0], xiB);

    // ---- layer 1: MI=32, MO=64, xiB -> xiA ----
    k_hT2<<<HTB, 256, 0, stream>>>(eord, ea, cw1[1], cb1[1], hT);
    k_edge5<32, 64, 32><<<dim3(EB5, 2), 256, 0, stream>>>(xiB, hT, w2t1, srcS, msgA, msgB);
    k_agg<32, 64, 32><<<(NN * 64 + 255) / 256, 256, 0, stream>>>(msgA, msgB, rowptr, xiB, croot[1], cbias[1], xiA);

    // ---- layer 2: MI=64, MO=64, xiA -> xiB ----
    k_hT2<<<HTB, 256, 0, stream>>>(eord, ea, cw1[2], cb1[2], hT);
    k_edge5<64, 64, 64><<<dim3(EB5, 2), 256, 0, stream>>>(xiA, hT, w2t2, srcS, msgA, msgB);
    k_agg<64, 64, 64><<<(NN * 64 + 255) / 256, 256, 0, stream>>>(msgA, msgB, rowptr, xiA, croot[2], cbias[2], xiB);

    // ---- pooling + MLP ----
    k_pool_s<<<(NN * 72 + 255) / 256, 256, 0, stream>>>(xiB, x, n2s, xs_sum, cs);
    k_pool_g<<<(NS * 72 + 255) / 256, 256, 0, stream>>>(xs_sum, cs, s2g, xg_sum, cg);
    k_fc<<<1, 128, 0, stream>>>(xg_sum, cg, fc1w, fc1b, fc2w, fc2b, fc3w, fc3b, (float*)d_out);
}

// Round 11
// 313.022 us; speedup vs baseline: 1.2921x; 1.2712x over previous
//
#include <hip/hip_runtime.h>
#include <hip/hip_bf16.h>
#include <cmath>

#define NN 20000   // nodes
#define NE 60000   // edges
#define NS 3000    // subgraphs
#define NG 128     // graphs
#define HIDN 128   // hidden dim of edge-attr MLP
#define SCB 79     // scan blocks = ceil(NN/256)

typedef float f32x16 __attribute__((ext_vector_type(16)));
typedef _Float16 f16x8 __attribute__((ext_vector_type(8)));

__device__ __forceinline__ float eluf(float v) { return v > 0.f ? v : expm1f(v); }

// async global->LDS, 16B per lane; lds ptr must be wave-uniform (HW writes base + lane*16)
__device__ __forceinline__ void gload_lds16(const void* g, void* l) {
    __builtin_amdgcn_global_load_lds(
        (const __attribute__((address_space(1))) unsigned int*)g,
        (__attribute__((address_space(3))) unsigned int*)l, 16, 0, 0);
}

// counted vmcnt waits (literal immediates required in asm)
template <int N> struct VmWait;
template <> struct VmWait<0>  { static __device__ __forceinline__ void run() { asm volatile("s_waitcnt vmcnt(0)"  ::: "memory"); } };
template <> struct VmWait<12> { static __device__ __forceinline__ void run() { asm volatile("s_waitcnt vmcnt(12)" ::: "memory"); } };
template <> struct VmWait<16> { static __device__ __forceinline__ void run() { asm volatile("s_waitcnt vmcnt(16)" ::: "memory"); } };
template <> struct VmWait<40> { static __device__ __forceinline__ void run() { asm volatile("s_waitcnt vmcnt(40)" ::: "memory"); } };

// ================= one-time edge sort by dst (counting sort) =================
__global__ void k_hist(const int* __restrict__ dst, int* __restrict__ deg) {
    int e = blockIdx.x * 256 + threadIdx.x;
    if (e < NE) atomicAdd(&deg[dst[e]], 1);
}

__global__ void k_scan1(const int* __restrict__ deg, int* __restrict__ bsum) {
    __shared__ int s[256];
    const int t = threadIdx.x;
    int i = blockIdx.x * 256 + t;
    s[t] = (i < NN) ? deg[i] : 0;
    __syncthreads();
#pragma unroll
    for (int off = 128; off > 0; off >>= 1) {
        if (t < off) s[t] += s[t + off];
        __syncthreads();
    }
    if (t == 0) bsum[blockIdx.x] = s[0];
}

__global__ void k_scan2(const int* __restrict__ bsum, int* __restrict__ boff) {
    __shared__ int s[SCB];
    const int t = threadIdx.x;
    if (t < SCB) s[t] = bsum[t];
    __syncthreads();
    if (t == 0) {
        int acc = 0;
        for (int i = 0; i < SCB; ++i) { int v = s[i]; s[i] = acc; acc += v; }
    }
    __syncthreads();
    if (t < SCB) boff[t] = s[t];
}

__global__ void k_scan3(const int* __restrict__ deg, const int* __restrict__ boff,
                        int* __restrict__ rowptr) {
    __shared__ int s[256];
    const int t = threadIdx.x;
    int i = blockIdx.x * 256 + t;
    int v = (i < NN) ? deg[i] : 0;
    s[t] = v;
    __syncthreads();
#pragma unroll
    for (int off = 1; off < 256; off <<= 1) {
        int a = (t >= off) ? s[t - off] : 0;
        __syncthreads();
        s[t] += a;
        __syncthreads();
    }
    if (i < NN) rowptr[i + 1] = boff[blockIdx.x] + s[t];
    if (i == 0) rowptr[0] = 0;
}

__global__ void k_scatter(const int* __restrict__ src, const int* __restrict__ dst,
                          const int* __restrict__ rowptr, int* __restrict__ tmp,
                          int* __restrict__ eord, int* __restrict__ srcS) {
    int e = blockIdx.x * 256 + threadIdx.x;
    if (e >= NE) return;
    int d = dst[e];
    int pos = rowptr[d] + atomicAdd(&tmp[d], 1);
    eord[pos] = e;
    srcS[pos] = src[e];
}

// ---------------- hT[j][es] = relu(ea[eord[es]] @ w1 + b1)  (128 x E fp16, transposed) --------
__global__ void k_hT2(const int* __restrict__ eord, const float* __restrict__ ea,
                      const float* __restrict__ w1, const float* __restrict__ b1,
                      _Float16* __restrict__ hT) {
    __shared__ float sea[64][5];
    const int t  = threadIdx.x;
    const int eb = blockIdx.x * 64;
    for (int i = t; i < 320; i += 256) {
        int el = i / 5, d = i % 5;
        int es = eb + el;
        int e = (es < NE) ? eord[es] : 0;
        sea[el][d] = ea[e * 5 + d];
    }
    __syncthreads();
    const int w = t >> 6, lane = t & 63;
    const int es = eb + lane;
    const float a0 = sea[lane][0], a1 = sea[lane][1], a2 = sea[lane][2],
                a3 = sea[lane][3], a4 = sea[lane][4];
#pragma unroll 4
    for (int jj = 0; jj < 32; ++jj) {
        const int j = w * 32 + jj;
        float s = b1[j];
        s = fmaf(a0, w1[0 * HIDN + j], s);
        s = fmaf(a1, w1[1 * HIDN + j], s);
        s = fmaf(a2, w1[2 * HIDN + j], s);
        s = fmaf(a3, w1[3 * HIDN + j], s);
        s = fmaf(a4, w1[4 * HIDN + j], s);
        if (es < NE) hT[(size_t)j * NE + es] = (_Float16)fmaxf(s, 0.f);
    }
}

// ---------------- w2t[o][kg] = f16( kg<128*MI ? w2[kg*MO+o] : b2[(kg-128MI)*MO+o] ) ----------------
template <int MI, int MO>
__global__ void k_w2t(const float* __restrict__ w2, const float* __restrict__ b2,
                      _Float16* __restrict__ w2t) {
    constexpr int KP = 129 * MI;
    constexpr int KF = 128 * MI;
    int idx = blockIdx.x * 256 + threadIdx.x;
    if (idx >= MO * KP) return;
    int o = idx / KP, kg = idx % KP;
    float v = (kg < KF) ? w2[(size_t)kg * MO + o] : b2[(kg - KF) * MO + o];
    w2t[idx] = (_Float16)v;
}

// ---------------- x16h[n][i] = f16(x[n][i]), i<16 ----------------
__global__ void k_x16h(const float* __restrict__ x, _Float16* __restrict__ xh) {
    int idx = blockIdx.x * 256 + threadIdx.x;
    if (idx >= NN * 16) return;
    int n = idx >> 4, i = idx & 15;
    xh[idx] = (_Float16)x[n * 24 + i];
}

// ---------------- MFMA edge kernel: fp16 A/B, in-block K-split, counted-vmcnt pipeline ------
// msg[j,o] = sum_kg G[j,kg]*w2t[o][kg],  G[j, k*MI+i] = hfac(j,k)*xi[srcS[j],i]
// Block = 4 waves (mg x kh): wave = 64 edges x full MO x k-half [kh*64, kh*64+64).
// B chunks (16KB) double-buffered via global_load_lds; barriers use COUNTED vmcnt.
// A-gen: f16x8 packed mul (v_pk_mul_f16) - no cvt, half the VALU of the f32 path.
template <int MI, int MO, int XS>
__global__ __launch_bounds__(256, 2) void k_edge6(
    const _Float16* __restrict__ xi, const _Float16* __restrict__ hT,
    const _Float16* __restrict__ w2t, const int* __restrict__ srcS,
    float* __restrict__ msg) {
    constexpr int PH  = MI / 16;        // K-steps per k value
    constexpr int KP  = 129 * MI;       // w2t row length
    constexpr int NT  = MO / 32;        // N tiles
    constexpr int CH  = 16 / (PH * NT); // k values per 16-item chunk
    constexpr int NCH = 64 / CH;        // chunks per k-half
    constexpr int VMK = 8 + 2 * CH;     // per-wave VMEM ops per iteration
    static_assert(CH * PH * NT == 16, "ITEMS must be 16");

    __shared__ __align__(16) _Float16 sb[2][2][16 * 512];   // [kh][dbuf][16KB] = 64KB

    const int lane = threadIdx.x & 63;
    const int w    = threadIdx.x >> 6;
    const int mg   = w & 1;             // edge-group
    const int kh   = w >> 1;            // k-half
    const int lo5  = lane & 31;
    const int hi   = lane >> 5;
    const int e0   = blockIdx.x * 128 + mg * 64;
    const int kb   = kh * 64;

    const int rc0 = min(e0 + lo5, NE - 1);
    const int rc1 = min(e0 + 32 + lo5, NE - 1);
    const int s0 = srcS[rc0];
    const int s1 = srcS[rc1];

    // x fragments resident as packed f16 (PH x 4 VGPRs per row)
    f16x8 xr0[PH], xr1[PH];
    {
        const _Float16* xb0 = xi + (size_t)s0 * XS + hi * 8;
        const _Float16* xb1 = xi + (size_t)s1 * XS + hi * 8;
#pragma unroll
        for (int p = 0; p < PH; ++p) {
            xr0[p] = *reinterpret_cast<const f16x8*>(xb0 + p * 16);
            xr1[p] = *reinterpret_cast<const f16x8*>(xb1 + p * 16);
        }
    }

    f32x16 acc[2][NT];
#pragma unroll
    for (int m = 0; m < 2; ++m)
#pragma unroll
        for (int n = 0; n < NT; ++n)
#pragma unroll
            for (int i = 0; i < 16; ++i) acc[m][n][i] = 0.f;

    // stage one 16KB chunk for this k-half; the 2 mg waves split the 16 items
    auto stage = [&](int buf, int kc) {
#pragma unroll
        for (int jj = 0; jj < 8; ++jj) {
            const int j  = mg + jj * 2;
            const int n  = j % NT;
            const int kp = j / NT;
            const int p  = kp % PH;
            const int kk = kp / PH;
            gload_lds16(w2t + (size_t)(n * 32 + lo5) * KP
                            + (size_t)(kb + kc + kk) * MI + p * 16 + hi * 8,
                        &sb[kh][buf][j * 512]);
        }
    };

    _Float16 hc0[CH], hc1[CH], hn0[CH], hn1[CH];

    stage(0, 0);
#pragma unroll
    for (int kk = 0; kk < CH; ++kk) {
        hc0[kk] = hT[(size_t)(kb + kk) * NE + rc0];
        hc1[kk] = hT[(size_t)(kb + kk) * NE + rc1];
    }

    for (int c = 0; c < NCH; ++c) {
        const bool pf = (c + 1 < NCH);
        if (pf) {
            stage((c + 1) & 1, (c + 1) * CH);
#pragma unroll
            for (int kk = 0; kk < CH; ++kk) {
                hn0[kk] = hT[(size_t)(kb + (c + 1) * CH + kk) * NE + rc0];
                hn1[kk] = hT[(size_t)(kb + (c + 1) * CH + kk) * NE + rc1];
            }
        }
        if (pf) VmWait<VMK>::run(); else VmWait<0>::run();
        __builtin_amdgcn_s_barrier();
        __builtin_amdgcn_sched_barrier(0);
        asm volatile("" ::: "memory");

        const _Float16* sbc = &sb[kh][c & 1][0];
#pragma unroll
        for (int kk = 0; kk < CH; ++kk) {
            const _Float16 hv0 = hc0[kk];
            const _Float16 hv1 = hc1[kk];
            const f16x8 h80 = {hv0, hv0, hv0, hv0, hv0, hv0, hv0, hv0};
            const f16x8 h81 = {hv1, hv1, hv1, hv1, hv1, hv1, hv1, hv1};
#pragma unroll
            for (int p = 0; p < PH; ++p) {
                const f16x8 af0 = xr0[p] * h80;     // 4 x v_pk_mul_f16
                const f16x8 af1 = xr1[p] * h81;
#pragma unroll
                for (int n = 0; n < NT; ++n) {
                    const f16x8 bv = *reinterpret_cast<const f16x8*>(
                        &sbc[((kk * PH + p) * NT + n) * 512 + lane * 8]);
                    acc[0][n] = __builtin_amdgcn_mfma_f32_32x32x16_f16(af0, bv, acc[0][n], 0, 0, 0);
                    acc[1][n] = __builtin_amdgcn_mfma_f32_32x32x16_f16(af1, bv, acc[1][n], 0, 0, 0);
                }
            }
        }
        __builtin_amdgcn_sched_barrier(0);
        asm volatile("" ::: "memory");
        __builtin_amdgcn_s_barrier();
        if (pf) {
#pragma unroll
            for (int kk = 0; kk < CH; ++kk) { hc0[kk] = hn0[kk]; hc1[kk] = hn1[kk]; }
        }
    }

    // k == 128 tail (folded b2 term, hfac = 1) — kh==1 only, direct global B
    if (kh == 1) {
#pragma unroll
        for (int p = 0; p < PH; ++p) {
#pragma unroll
            for (int n = 0; n < NT; ++n) {
                const f16x8 bv = *reinterpret_cast<const f16x8*>(
                    w2t + (size_t)(n * 32 + lo5) * KP + (size_t)128 * MI + p * 16 + hi * 8);
                acc[0][n] = __builtin_amdgcn_mfma_f32_32x32x16_f16(xr0[p], bv, acc[0][n], 0, 0, 0);
                acc[1][n] = __builtin_amdgcn_mfma_f32_32x32x16_f16(xr1[p], bv, acc[1][n], 0, 0, 0);
            }
        }
    }

    // ---- merge kh pair via LDS: red[tile][i][lane] layout = conflict-free ----
    __syncthreads();
    float* red = reinterpret_cast<float*>(&sb[0][0][0]);   // 8 tiles x 1024 f32 = 32KB
    if (kh == 1) {
#pragma unroll
        for (int m = 0; m < 2; ++m)
#pragma unroll
            for (int n = 0; n < NT; ++n) {
                float* d = red + (size_t)((mg * 2 + m) * NT + n) * 1024 + lane;
#pragma unroll
                for (int i = 0; i < 16; ++i) d[i * 64] = acc[m][n][i];
            }
    }
    __syncthreads();
    if (kh == 0) {
#pragma unroll
        for (int m = 0; m < 2; ++m)
#pragma unroll
            for (int n = 0; n < NT; ++n) {
                const float* s = red + (size_t)((mg * 2 + m) * NT + n) * 1024 + lane;
#pragma unroll
                for (int i = 0; i < 16; ++i) acc[m][n][i] += s[i * 64];
            }
        // store: C layout col = lane&31, row = (reg&3) + 8*(reg>>2) + 4*(lane>>5)
#pragma unroll
        for (int m = 0; m < 2; ++m)
#pragma unroll
            for (int q = 0; q < 4; ++q)
#pragma unroll
                for (int a = 0; a < 4; ++a) {
                    const int e = e0 + m * 32 + 4 * hi + 8 * q + a;
                    if (e < NE) {
#pragma unroll
                        for (int n = 0; n < NT; ++n)
                            msg[(size_t)e * MO + n * 32 + lo5] = acc[m][n][4 * q + a];
                    }
                }
    }
}

// ---------------- agg: out = elu(bias + xi@root + CSR-sum msg); writes f32 + f16 copies ------
template <int MI, int MO, int XS>
__global__ void k_agg(const float* __restrict__ msg, const int* __restrict__ rowptr,
                      const float* __restrict__ xi, const float* __restrict__ root,
                      const float* __restrict__ bias, float* __restrict__ out,
                      _Float16* __restrict__ outh) {
    int idx = blockIdx.x * 256 + threadIdx.x;
    if (idx >= NN * MO) return;
    int n = idx / MO, o = idx % MO;
    float s = bias[o];
#pragma unroll
    for (int i = 0; i < MI; ++i) s = fmaf(xi[(size_t)n * XS + i], root[i * MO + o], s);
    const int j0 = rowptr[n], j1 = rowptr[n + 1];
    for (int j = j0; j < j1; ++j) s += msg[(size_t)j * MO + o];
    float r = eluf(s);
    out[idx] = r;
    outh[idx] = (_Float16)r;
}

// ---------------- pool nodes -> subgraphs (sum + count) ----------------
__global__ void k_pool_s(const float* __restrict__ xi, const float* __restrict__ x,
                         const int* __restrict__ n2s, float* __restrict__ xs_sum,
                         float* __restrict__ cs) {
    int idx = blockIdx.x * 256 + threadIdx.x;
    if (idx >= NN * 72) return;
    int n = idx / 72, j = idx % 72;
    float v = (j < 64) ? xi[n * 64 + j] : x[n * 24 + 16 + (j - 64)];
    int s = n2s[n];
    atomicAdd(&xs_sum[s * 72 + j], v);
    if (j == 0) atomicAdd(&cs[s], 1.f);
}

// ---------------- pool subgraphs -> graphs (mean of means) ----------------
__global__ void k_pool_g(const float* __restrict__ xs_sum, const float* __restrict__ cs,
                         const int* __restrict__ s2g, float* __restrict__ xg_sum,
                         float* __restrict__ cg) {
    int idx = blockIdx.x * 256 + threadIdx.x;
    if (idx >= NS * 72) return;
    int s = idx / 72, j = idx % 72;
    float v = xs_sum[s * 72 + j] / fmaxf(cs[s], 1.f);
    int g = s2g[s];
    atomicAdd(&xg_sum[g * 72 + j], v);
    if (j == 0) atomicAdd(&cg[g], 1.f);
}

// ---------------- final MLP: 72 -> 36 -> 18 -> 1 ----------------
__global__ void k_fc(const float* __restrict__ xg_sum, const float* __restrict__ cg,
                     const float* __restrict__ w1, const float* __restrict__ b1,
                     const float* __restrict__ w2, const float* __restrict__ b2,
                     const float* __restrict__ w3, const float* __restrict__ b3,
                     float* __restrict__ out) {
    int g = threadIdx.x;
    if (g >= NG) return;
    float inv = 1.f / fmaxf(cg[g], 1.f);
    float v[72];
#pragma unroll
    for (int j = 0; j < 72; ++j) v[j] = xg_sum[g * 72 + j] * inv;
    float h1[36];
#pragma unroll
    for (int o = 0; o < 36; ++o) {
        float s = b1[o];
#pragma unroll
        for (int i = 0; i < 72; ++i) s = fmaf(v[i], w1[i * 36 + o], s);
        h1[o] = eluf(s);
    }
    float h2[18];
#pragma unroll
    for (int o = 0; o < 18; ++o) {
        float s = b2[o];
#pragma unroll
        for (int i = 0; i < 36; ++i) s = fmaf(h1[i], w2[i * 18 + o], s);
        h2[o] = eluf(s);
    }
    float s = b3[0];
#pragma unroll
    for (int i = 0; i < 18; ++i) s = fmaf(h2[i], w3[i], s);
    out[g] = s;
}

// ---------------- launcher ----------------
extern "C" void kernel_launch(void* const* d_in, const int* in_sizes, int n_in,
                              void* d_out, int out_size, void* d_ws, size_t ws_size,
                              hipStream_t stream) {
    const float* x   = (const float*)d_in[0];
    const int*   ei  = (const int*)d_in[1];
    const float* ea  = (const float*)d_in[2];
    const int*   n2s = (const int*)d_in[3];
    const int*   s2g = (const int*)d_in[4];
    const int* src = ei;
    const int* dst = ei + NE;

    const float* cw1[3]   = {(const float*)d_in[5],  (const float*)d_in[11], (const float*)d_in[17]};
    const float* cb1[3]   = {(const float*)d_in[6],  (const float*)d_in[12], (const float*)d_in[18]};
    const float* cw2[3]   = {(const float*)d_in[7],  (const float*)d_in[13], (const float*)d_in[19]};
    const float* cb2[3]   = {(const float*)d_in[8],  (const float*)d_in[14], (const float*)d_in[20]};
    const float* croot[3] = {(const float*)d_in[9],  (const float*)d_in[15], (const float*)d_in[21]};
    const float* cbias[3] = {(const float*)d_in[10], (const float*)d_in[16], (const float*)d_in[22]};
    const float* fc1w = (const float*)d_in[23];
    const float* fc1b = (const float*)d_in[24];
    const float* fc2w = (const float*)d_in[25];
    const float* fc2b = (const float*)d_in[26];
    const float* fc3w = (const float*)d_in[27];
    const float* fc3b = (const float*)d_in[28];

    // ---- workspace layout (bytes, 16-aligned) ----
    char* W = (char*)d_ws;
    _Float16* hT    = (_Float16*)(W);                 // 128*NE*2   = 15,360,000
    float*    xiA   = (float*)(W + 15360000);         // NN*64*4    =  5,120,000
    float*    xiB   = (float*)(W + 20480000);         // NN*64*4    =  5,120,000
    _Float16* xiAh  = (_Float16*)(W + 25600000);      // NN*64*2    =  2,560,000
    _Float16* xiBh  = (_Float16*)(W + 28160000);      // NN*64*2    =  2,560,000
    _Float16* x16h  = (_Float16*)(W + 30720000);      // NN*16*2    =    640,000
    float*    msg   = (float*)(W + 31360000);         // NE*64*4    = 15,360,000
    float*    xs_sum= (float*)(W + 46720000);         // NS*72*4    =    864,000
    float*    cs    = (float*)(W + 47584000);         // NS*4       =     12,000
    float*    xg_sum= (float*)(W + 47596000);         // NG*72*4    =     36,864
    float*    cg    = (float*)(W + 47632864);         // NG*4       =        512
    _Float16* w2t0  = (_Float16*)(W + 47633376);      // 32*2064*2  =    132,096
    _Float16* w2t1  = (_Float16*)(W + 47765472);      // 64*4128*2  =    528,384
    _Float16* w2t2  = (_Float16*)(W + 48293856);      // 64*8256*2  =  1,056,768
    int*      deg   = (int*)(W + 49350624);           // NN*4       =     80,000
    int*      tmp   = (int*)(W + 49430624);           // NN*4       =     80,000
    int*      rowptr= (int*)(W + 49510624);           // (NN+1)*4   ->    80,016
    int*      eord  = (int*)(W + 49590640);           // NE*4       =    240,000
    int*      srcS  = (int*)(W + 49830640);           // NE*4       =    240,000
    int*      bsum  = (int*)(W + 50070640);           // SCB*4
    int*      boff  = (int*)(W + 50070960);           // SCB*4
    // total ~50,071,280 bytes

    // zero: pooling accumulators + sort counters
    hipMemsetAsync(xs_sum, 0, (size_t)(NS * 72 + NS) * 4 + (size_t)(NG * 72 + NG) * 4, stream);
    hipMemsetAsync(deg, 0, 160000, stream);

    // ---- one-time edge sort by dst (hierarchical scan) ----
    k_hist<<<(NE + 255) / 256, 256, 0, stream>>>(dst, deg);
    k_scan1<<<SCB, 256, 0, stream>>>(deg, bsum);
    k_scan2<<<1, 128, 0, stream>>>(bsum, boff);
    k_scan3<<<SCB, 256, 0, stream>>>(deg, boff, rowptr);
    k_scatter<<<(NE + 255) / 256, 256, 0, stream>>>(src, dst, rowptr, tmp, eord, srcS);

    // prep: transposed f16 W2 (b2 folded as k==128), f16 x16
    k_w2t<16, 32><<<(32 * 129 * 16 + 255) / 256, 256, 0, stream>>>(cw2[0], cb2[0], w2t0);
    k_w2t<32, 64><<<(64 * 129 * 32 + 255) / 256, 256, 0, stream>>>(cw2[1], cb2[1], w2t1);
    k_w2t<64, 64><<<(64 * 129 * 64 + 255) / 256, 256, 0, stream>>>(cw2[2], cb2[2], w2t2);
    k_x16h<<<(NN * 16 + 255) / 256, 256, 0, stream>>>(x, x16h);

    const int EB = (NE + 127) / 128;   // 469 blocks of 4 waves
    const int HTB = (NE + 63) / 64;    // 938

    // ---- layer 0: MI=16, MO=32 ----
    k_hT2<<<HTB, 256, 0, stream>>>(eord, ea, cw1[0], cb1[0], hT);
    k_edge6<16, 32, 16><<<EB, 256, 0, stream>>>(x16h, hT, w2t0, srcS, msg);
    k_agg<16, 32, 24><<<(NN * 32 + 255) / 256, 256, 0, stream>>>(msg, rowptr, x, croot[0], cbias[0], xiB, xiBh);

    // ---- layer 1: MI=32, MO=64 ----
    k_hT2<<<HTB, 256, 0, stream>>>(eord, ea, cw1[1], cb1[1], hT);
    k_edge6<32, 64, 32><<<EB, 256, 0, stream>>>(xiBh, hT, w2t1, srcS, msg);
    k_agg<32, 64, 32><<<(NN * 64 + 255) / 256, 256, 0, stream>>>(msg, rowptr, xiB, croot[1], cbias[1], xiA, xiAh);

    // ---- layer 2: MI=64, MO=64 ----
    k_hT2<<<HTB, 256, 0, stream>>>(eord, ea, cw1[2], cb1[2], hT);
    k_edge6<64, 64, 64><<<EB, 256, 0, stream>>>(xiAh, hT, w2t2, srcS, msg);
    k_agg<64, 64, 64><<<(NN * 64 + 255) / 256, 256, 0, stream>>>(msg, rowptr, xiA, croot[2], cbias[2], xiB, xiBh);

    // ---- pooling + MLP ----
    k_pool_s<<<(NN * 72 + 255) / 256, 256, 0, stream>>>(xiB, x, n2s, xs_sum, cs);
    k_pool_g<<<(NS * 72 + 255) / 256, 256, 0, stream>>>(xs_sum, cs, s2g, xg_sum, cg);
    k_fc<<<1, 128, 0, stream>>>(xg_sum, cg, fc1w, fc1b, fc2w, fc2b, fc3w, fc3b, (float*)d_out);
}